// Round 7
// baseline (264.982 us; speedup 1.0000x reference)
//
#include <hip/hip_runtime.h>
#include <math.h>

#define BB 16
#define TT 2048
#define CC 1024
#define HH 64
#define MTOT (BB*TT)

typedef _Float16 f16;
typedef _Float16 f16x4 __attribute__((ext_vector_type(4)));
typedef _Float16 f16x8 __attribute__((ext_vector_type(8)));
typedef float f32x4 __attribute__((ext_vector_type(4)));

// ws layout (f16 element offsets):
//   Wt [192][1024]   n-major transposed weights (q|k|v)
//   q  [32768][64]   row-major, pre-scaled by 0.125/ln2 (exp2 softmax)
//   k  [32768][64]   row-major
//   vT [64][32768]   h-major transposed v
#define WT_OFF 0
#define Q_OFF  196608
#define K_OFF  (Q_OFF + (size_t)MTOT*HH)
#define VT_OFF (K_OFF + (size_t)MTOT*HH)

#define QSCALE 0.18033688011112042f   // (1/8) * (1/ln2)

__device__ __forceinline__ void async16(const void* g, void* l) {
    __builtin_amdgcn_global_load_lds(
        (const __attribute__((address_space(1))) unsigned int*)g,
        (__attribute__((address_space(3))) unsigned int*)l, 16, 0, 0);
}

__device__ __forceinline__ f16x8 cvt8(float4 u, float4 v) {
    f16x8 r;
    r[0] = (f16)u.x; r[1] = (f16)u.y; r[2] = (f16)u.z; r[3] = (f16)u.w;
    r[4] = (f16)v.x; r[5] = (f16)v.y; r[6] = (f16)v.z; r[7] = (f16)v.w;
    return r;
}

// ---------------- Kernel 0: W transpose + convert ----------------
__global__ __launch_bounds__(256) void prep_kernel(
    const float* __restrict__ Wq, const float* __restrict__ Wk,
    const float* __restrict__ Wv, f16* __restrict__ ws)
{
    int e = blockIdx.x * 256 + threadIdx.x;      // 196608 elems
    int ng = e >> 10, k = e & 1023;
    int which = ng >> 6, n = ng & 63;
    const float* W = (which == 0) ? Wq : (which == 1) ? Wk : Wv;
    ws[WT_OFF + e] = (f16)W[k * HH + n];
}

// ---------------- Kernel 1: QKV projection ----------------
// BM=64, N=192, BK=32, 512 blocks x 4 waves. Double-buffered LDS staging via
// global_load_lds, ONE barrier/iter: prefetch(it+1) issues after the barrier,
// so the next barrier's vmcnt(0) drain lands a full compute phase later ->
// the x HBM stream is continuous. Wave w: n-tiles {3w..3w+2}, all 4 m-tiles.
__global__ __launch_bounds__(256, 2) void qkv_kernel(
    const float* __restrict__ x,
    const float* __restrict__ bq, const float* __restrict__ bk,
    const float* __restrict__ bv, f16* __restrict__ ws)
{
    __shared__ __align__(16) float Xs[2][64 * 32];   // 16 KB dbuf (alias Vt)
    __shared__ __align__(16) f16   Ws[2][192 * 32];  // 24 KB dbuf
    f16 (*Vt)[72] = (f16 (*)[72])Xs;                 // 9.2 KB alias, post-loop

    const f16* wt = ws + WT_OFF;
    const int tid  = threadIdx.x;
    const int lane = tid & 63, w = tid >> 6;
    const int c = lane & 15, g = lane >> 4;
    const int m0 = blockIdx.x * 64;

    f32x4 acc[4][3];
    #pragma unroll
    for (int mt = 0; mt < 4; ++mt)
        #pragma unroll
        for (int j = 0; j < 3; ++j) acc[mt][j] = (f32x4){0.f, 0.f, 0.f, 0.f};

    // stage k-slice it into buffer it&1
    #define STAGE(it) do {                                                  \
        int buf = (it) & 1;                                                 \
        int k0 = (it) * 32;                                                 \
        _Pragma("unroll")                                                   \
        for (int i = 0; i < 2; ++i) {         /* X: 512 granules (fp32) */  \
            int G0 = (w * 2 + i) * 64;                                      \
            int G = G0 + lane;                                              \
            int r = G >> 3, qs = G & 7;                                     \
            int qg = qs ^ (r & 7);                                          \
            async16(x + (size_t)(m0 + r) * CC + k0 + qg * 4,                \
                    &Xs[buf][G0 * 4]);                                      \
        }                                                                   \
        _Pragma("unroll")                                                   \
        for (int i = 0; i < 3; ++i) {         /* W: 768 granules (f16) */   \
            int G0 = (w * 3 + i) * 64;                                      \
            int G = G0 + lane;                                              \
            int r = G >> 2, qs = G & 3;                                     \
            int qg = qs ^ ((r ^ (r >> 2)) & 3);                             \
            async16(wt + (size_t)r * CC + k0 + qg * 8,                      \
                    &Ws[buf][G0 * 8]);                                      \
        }                                                                   \
    } while (0)

    STAGE(0);

    #pragma unroll 2
    for (int it = 0; it < 32; ++it) {
        __syncthreads();   // drains STAGE(it); prev readers of this buf done
        if (it < 31) STAGE(it + 1);
        const float* xb = Xs[it & 1];
        const f16*   wb = Ws[it & 1];

        f16x8 bfr[3];
        #pragma unroll
        for (int j = 0; j < 3; ++j) {
            int r = (3 * w + j) * 16 + c;
            int pos = g ^ ((c ^ (c >> 2)) & 3);
            bfr[j] = *(const f16x8*)(wb + r * 32 + pos * 8);
        }
        #pragma unroll
        for (int mt = 0; mt < 4; ++mt) {
            int r = mt * 16 + c;
            float4 f0 = *(const float4*)(xb + r * 32 + (((2 * g)     ^ (c & 7)) * 4));
            float4 f1 = *(const float4*)(xb + r * 32 + (((2 * g + 1) ^ (c & 7)) * 4));
            f16x8 a = cvt8(f0, f1);
            #pragma unroll
            for (int j = 0; j < 3; ++j)
                acc[mt][j] = __builtin_amdgcn_mfma_f32_16x16x32_f16(
                    a, bfr[j], acc[mt][j], 0, 0, 0);
        }
    }
    #undef STAGE
    __syncthreads();   // all Xs fragment reads done before Vt alias writes

    // epilogue: C/D row = 4g+r (in 16-tile), col = nt*16+c
    #pragma unroll
    for (int j = 0; j < 3; ++j) {
        int nt = 3 * w + j;
        int plane = nt >> 2;             // 0=q 1=k 2=v
        int h = (nt & 3) * 16 + c;
        if (plane == 0) {
            float bias = bq[h];
            #pragma unroll
            for (int mt = 0; mt < 4; ++mt)
                #pragma unroll
                for (int r = 0; r < 4; ++r) {
                    int m = m0 + mt * 16 + 4 * g + r;
                    ws[Q_OFF + (size_t)m * HH + h] =
                        (f16)((acc[mt][j][r] + bias) * QSCALE);
                }
        } else if (plane == 1) {
            float bias = bk[h];
            #pragma unroll
            for (int mt = 0; mt < 4; ++mt)
                #pragma unroll
                for (int r = 0; r < 4; ++r) {
                    int m = m0 + mt * 16 + 4 * g + r;
                    ws[K_OFF + (size_t)m * HH + h] = (f16)(acc[mt][j][r] + bias);
                }
        } else {
            float bias = bv[h];
            #pragma unroll
            for (int mt = 0; mt < 4; ++mt)
                #pragma unroll
                for (int r = 0; r < 4; ++r)
                    Vt[h][mt * 16 + 4 * g + r] = (f16)(acc[mt][j][r] + bias);
        }
    }
    __syncthreads();
    {   // coalesced vT write
        int h = tid >> 2, seg = tid & 3;
        f16* dst = ws + VT_OFF + (size_t)h * MTOT + m0 + seg * 16;
        *(f16x8*)dst       = *(f16x8*)&Vt[h][seg * 16];
        *(f16x8*)(dst + 8) = *(f16x8*)&Vt[h][seg * 16 + 8];
    }
}

// ---------------- Kernel 2: causal flash attention (S^T, BQ=32) ----------------
// 1024 blocks x 2 waves (4 blocks/CU -> 4 independent barrier domains).
// Wave w owns q-rows [q0+16w, +16). S^T = K·Q^T -> P packs to LDS with
// ds_write_b64, reads back as contiguous B-frags for O^T = V^T·P^T. Exp2-only
// softmax (1/ln2 folded into q). K/V dbuf, ONE barrier per 64-wide s-tile.
__global__ __launch_bounds__(128, 2) void attn_kernel(
    const f16* __restrict__ ws, float* __restrict__ out)
{
    const f16* qp = ws + Q_OFF;
    const f16* kp = ws + K_OFF;
    const f16* vt = ws + VT_OFF;

    __shared__ __align__(16) f16 Ks[2][64 * 64];    // 16 KB, XOR-swizzled
    __shared__ __align__(16) f16 Vs[2][64 * 64];    // 16 KB, XOR-swizzled
    __shared__ __align__(16) f16 PsT[2][16][72];    // 4.5 KB wave-private P^T

    const int tid  = threadIdx.x;
    const int lane = tid & 63, w = tid >> 6;
    const int c = lane & 15, g = lane >> 4;

    // swizzle: XCD r8 gets batches 2r8,2r8+1; blocks i,i+512 complementary
    const int id = blockIdx.x;
    const int r8 = id & 7, j = id >> 3;
    const int half = j >> 6, qr = j & 63;
    const int b  = 2 * r8 + half;
    const int qi = half ? (63 - qr) : qr;        // q-tile (32 rows) 0..63
    const int q0 = qi * 32;
    const size_t rowbase = (size_t)b * TT;

    // Q B-fragments (held whole kernel): B[k=h][n=q-row]
    f16x8 bq_[2];
    {
        const f16* qrow = qp + (rowbase + q0 + w * 16 + c) * HH + g * 8;
        bq_[0] = *(const f16x8*)(qrow);
        bq_[1] = *(const f16x8*)(qrow + 32);
    }

    f32x4 o[4];   // O^T h-tiles (C layout: row=h=ht*16+4g+rr, col=q=c)
    #pragma unroll
    for (int ht = 0; ht < 4; ++ht) o[ht] = (f32x4){0.f, 0.f, 0.f, 0.f};
    float l_acc = 0.f;

    // stage K rows + V^T cols [st*64, +64) into buffer st&1: 4+4 calls/wave
    #define STAGE_KV(st) do {                                              \
        int buf = (st) & 1;                                                \
        _Pragma("unroll")                                                  \
        for (int i = 0; i < 4; ++i) {                                      \
            int G0 = (w * 4 + i) * 64;                                     \
            int G = G0 + lane;                                             \
            int r = G >> 3, qs = G & 7;                                    \
            int sw = (qs ^ (r & 7)) << 3;                                  \
            async16(kp + (rowbase + (st) * 64 + r) * HH + sw, &Ks[buf][G0 * 8]); \
            async16(vt + (size_t)r * MTOT + rowbase + (st) * 64 + sw, &Vs[buf][G0 * 8]); \
        }                                                                  \
    } while (0)

    const int nst = (qi >> 1) + 1;
    STAGE_KV(0);

    for (int st = 0; st < nst; ++st) {
        __syncthreads();   // drains STAGE_KV(st); prev readers of buf done
        if (st + 1 < nst) STAGE_KV(st + 1);
        const f16* kb = Ks[st & 1];
        const f16* vb = Vs[st & 1];
        const bool diag = (st == nst - 1);
        const int tmax = diag ? (w + 2 * (qi & 1)) : 3;  // skip masked subtiles
        const int rel  = q0 + 16 * w + c - st * 64;      // diag mask threshold

        // S^T subtiles: A = K rows, B = Q rows; exp2; pack to PsT[q][s]
        float lp = 0.f;
        #pragma unroll
        for (int t = 0; t < 4; ++t) {
            f16x4 pv;
            if (t <= tmax) {
                int r = t * 16 + c;
                f16x8 a0 = *(const f16x8*)(kb + r * 64 + (((g)     ^ (c & 7)) << 3));
                f16x8 a1 = *(const f16x8*)(kb + r * 64 + (((4 + g) ^ (c & 7)) << 3));
                f32x4 s = (f32x4){0.f, 0.f, 0.f, 0.f};
                s = __builtin_amdgcn_mfma_f32_16x16x32_f16(a0, bq_[0], s, 0, 0, 0);
                s = __builtin_amdgcn_mfma_f32_16x16x32_f16(a1, bq_[1], s, 0, 0, 0);
                #pragma unroll
                for (int rr = 0; rr < 4; ++rr) {
                    float p = (diag && (t * 16 + 4 * g + rr > rel))
                                ? 0.f : exp2f(s[rr]);
                    lp += p;
                    pv[rr] = (f16)p;
                }
            } else {
                pv = (f16x4){(f16)0.f, (f16)0.f, (f16)0.f, (f16)0.f};
            }
            *(f16x4*)&PsT[w][c][t * 16 + 4 * g] = pv;   // one ds_write_b64
        }
        // l: sum the 4 g-groups holding q-col c
        lp += __shfl_xor(lp, 16);
        lp += __shfl_xor(lp, 32);
        l_acc += lp;

        // O^T += V^T · P^T : B-frags contiguous from PsT (in-wave RAW)
        f16x8 pb0 = *(const f16x8*)&PsT[w][c][g * 8];
        f16x8 pb1 = *(const f16x8*)&PsT[w][c][32 + g * 8];
        #pragma unroll
        for (int ht = 0; ht < 4; ++ht) {
            int r = ht * 16 + c;
            f16x8 va0 = *(const f16x8*)(vb + r * 64 + (((g)     ^ (c & 7)) << 3));
            f16x8 va1 = *(const f16x8*)(vb + r * 64 + (((4 + g) ^ (c & 7)) << 3));
            o[ht] = __builtin_amdgcn_mfma_f32_16x16x32_f16(va0, pb0, o[ht], 0, 0, 0);
            o[ht] = __builtin_amdgcn_mfma_f32_16x16x32_f16(va1, pb1, o[ht], 0, 0, 0);
        }
    }
    #undef STAGE_KV

    // epilogue: lane owns q-row q0+16w+c, cols ht*16+4g..+3 -> float4 stores
    float inv = 1.0f / l_acc;
    float* orow = out + (rowbase + q0 + w * 16 + c) * HH;
    #pragma unroll
    for (int ht = 0; ht < 4; ++ht) {
        float4 v;
        v.x = o[ht][0] * inv; v.y = o[ht][1] * inv;
        v.z = o[ht][2] * inv; v.w = o[ht][3] * inv;
        *(float4*)(orow + ht * 16 + 4 * g) = v;
    }
}

extern "C" void kernel_launch(void* const* d_in, const int* in_sizes, int n_in,
                              void* d_out, int out_size, void* d_ws, size_t ws_size,
                              hipStream_t stream) {
    const float* x  = (const float*)d_in[0];
    const float* Wq = (const float*)d_in[1];
    const float* bq = (const float*)d_in[2];
    const float* Wk = (const float*)d_in[3];
    const float* bk = (const float*)d_in[4];
    const float* Wv = (const float*)d_in[5];
    const float* bv = (const float*)d_in[6];
    f16*   ws  = (f16*)d_ws;
    float* out = (float*)d_out;

    prep_kernel<<<768, 256, 0, stream>>>(Wq, Wk, Wv, ws);
    qkv_kernel<<<MTOT / 64, 256, 0, stream>>>(x, bq, bk, bv, ws);
    attn_kernel<<<1024, 128, 0, stream>>>(ws, out);
}